// Round 11
// baseline (89.015 us; speedup 1.0000x reference)
//
#include <hip/hip_runtime.h>
#include <hip/hip_bf16.h>
#include <math.h>

#define NB 32
#define SEQT 512
#define DDIM 16
#define NWIN 510
#define NTOT (NB*NWIN)      // 16320
#define SLOPE 0.2f
#define NI 3                // instances per wave (saturation point per r7-r10)
#define GW 192              // windows per block (4 waves * 3 inst * 16)
#define NGR 85              // real groups: 85*192 = 16320 exactly
#define NGP 88              // padded to multiple of 8 for XCD mapping

typedef __attribute__((ext_vector_type(8))) short sh8;   // 8 bf16
typedef __attribute__((ext_vector_type(4))) float f4;

// ws byte offsets
#define W0B_OFF 0            // bf16 [16][64][32]   (k = 0..31 only)
#define W1B_OFF 65536        // bf16 [16][64][64]
#define W2B_OFF 196608       // bf16 [16][64][64]
#define WCOL_OFF 327680      // f32  [16][64]  = W0[d][h][32]
#define RED_OFF 331776       // f32  [340][16][2]
#define CNT_OFF 380928       // int counter (after red)
#define NPREP 164864

static __device__ __forceinline__ unsigned short bfb(float f){
    union { __hip_bfloat16 h; unsigned short u; } cv;
    cv.h = __float2bfloat16(f);
    return cv.u;
}
static __device__ __forceinline__ unsigned pk2(float a, float b){
    return (unsigned)bfb(a) | ((unsigned)bfb(b) << 16);
}

__global__ void prep(const float* __restrict__ W0, const float* __restrict__ W1,
                     const float* __restrict__ W2, unsigned char* __restrict__ wsb){
    int e = blockIdx.x*256 + threadIdx.x;
    if (e < 32768){
        unsigned short* W0b = (unsigned short*)(wsb + W0B_OFF);
        int d = e >> 11, r = e & 2047, h = r >> 5, k = r & 31;
        W0b[e] = bfb(W0[(d*64 + h)*33 + k]);
    } else if (e < 98304){
        ((unsigned short*)(wsb + W1B_OFF))[e - 32768] = bfb(W1[e - 32768]);
    } else if (e < 163840){
        ((unsigned short*)(wsb + W2B_OFF))[e - 98304] = bfb(W2[e - 98304]);
    } else if (e < NPREP){
        int i = e - 163840;
        int d = i >> 6, h = i & 63;
        ((float*)(wsb + WCOL_OFF))[i] = W0[(d*64 + h)*33 + 32];
    } else if (e == NPREP){
        *(int*)(wsb + CNT_OFF) = 0;          // reset tail counter every launch
    }
}

__global__ __launch_bounds__(256, 3) void mlp(
    const float* __restrict__ x,
    const float* __restrict__ bias0, const float* __restrict__ bias1,
    const float* __restrict__ bias2,
    const float* __restrict__ Wout, const float* __restrict__ boutp,
    unsigned char* __restrict__ wsb,
    float* __restrict__ red, float* __restrict__ out)
{
    // barrier-free main body: wave w owns rows [48w, 48w+48). 3 instances per wave.
    __shared__ __align__(16) unsigned char bufA[GW*128];   // h1 -> h2 (in-place), 24 KB
    __shared__ __align__(16) unsigned char bufB[GW*128];   // t1 -> t2 (in-place), 24 KB
    __shared__ int lastflag;

    const int tid  = threadIdx.x;
    const int lane = tid & 63;
    const int w    = tid >> 6;
    const int nl   = lane & 15;
    const int hi   = lane >> 4;
    const int rsw  = (nl & 7) << 4;

    // XCD-local decode: bid = (g&7) + 8*d + 128*(g>>3); all 16 d-blocks of a
    // group share bid%8 (same XCD under round-robin dispatch).
    const int bid = blockIdx.x;
    const int d   = (bid >> 3) & 15;
    const int g   = ((bid >> 7) << 3) | (bid & 7);
    if (g >= NGR) return;            // padded dummies exit before the tail

    const unsigned char* W0b = wsb + W0B_OFF + d*4096;
    const unsigned char* W1b = wsb + W1B_OFF + d*8192;
    const unsigned char* W2b = wsb + W2B_OFF + d*8192;

    int   bb[NI];
    float xxv[NI];
    union { uint4 u; sh8 s; } in[NI];
    #pragma unroll
    for (int i=0;i<NI;++i){
        int n = g*GW + 48*w + nl + 16*i;
        int b = n / NWIN, t = n - b*NWIN;
        bb[i] = b;
        const float* gp = x + (size_t)(b*SEQT + t)*DDIM + 8*hi;
        float4 p0 = ((const float4*)gp)[0];
        float4 p1 = ((const float4*)gp)[1];
        in[i].u.x = pk2(p0.x,p0.y); in[i].u.y = pk2(p0.z,p0.w);
        in[i].u.z = pk2(p1.x,p1.y); in[i].u.w = pk2(p1.z,p1.w);
        xxv[i] = x[(size_t)(b*SEQT + t + 2)*DDIM + d];
    }

    f4 aA[NI][4], aB[NI][4];

    // ---------------- L1 (K=32 MFMA + fp32 rank-1 for col 32) ----------------
    #pragma unroll
    for (int t=0;t<4;++t){
        float4 bv = *(const float4*)(bias0 + d*64 + 16*t + 4*hi);
        #pragma unroll
        for (int i=0;i<NI;++i) aA[i][t] = (f4){bv.x,bv.y,bv.z,bv.w};
    }
    __builtin_amdgcn_s_setprio(1);
    #pragma unroll
    for (int t=0;t<4;++t){
        sh8 af = *(const sh8*)&W0b[((16*t+nl)*32 + 8*hi)*2];
        #pragma unroll
        for (int i=0;i<NI;++i)
            aA[i][t] = __builtin_amdgcn_mfma_f32_16x16x32_bf16(af, in[i].s, aA[i][t], 0,0,0);
    }
    __builtin_amdgcn_s_setprio(0);

    // ---- E1: rank-1 + act -> bufA ; t1 = deriv1.*wcol -> bufB ----
    {
        const float* wcolp = (const float*)(wsb + WCOL_OFF) + d*64;
        #pragma unroll
        for (int t=0;t<4;++t){
            float4 wv = *(const float4*)(wcolp + 16*t + 4*hi);
            float wc[4] = {wv.x, wv.y, wv.z, wv.w};
            #pragma unroll
            for (int i=0;i<NI;++i){
                const int row = 48*w + nl + 16*i;
                float v[4], tv[4];
                #pragma unroll
                for (int r=0;r<4;++r){
                    float a = fmaf(wc[r], xxv[i], aA[i][t][r]);
                    v[r]  = fmaxf(a, SLOPE*a);
                    tv[r] = (a >= 0.f) ? wc[r] : SLOPE*wc[r];
                }
                uint2 ph; ph.x = pk2(v[0],v[1]);  ph.y = pk2(v[2],v[3]);
                *(uint2*)&bufA[row*128 + ((32*t + 8*hi) ^ rsw)] = ph;
                uint2 pt; pt.x = pk2(tv[0],tv[1]); pt.y = pk2(tv[2],tv[3]);
                *(uint2*)&bufB[row*128 + ((32*t + 8*hi) ^ rsw)] = pt;
            }
        }
    }

    // ---------------- G2: L2 fwd + T2 tangent, shared A-frags ----------------
    #pragma unroll
    for (int t=0;t<4;++t){
        float4 bv = *(const float4*)(bias1 + d*64 + 16*t + 4*hi);
        #pragma unroll
        for (int i=0;i<NI;++i){
            aA[i][t] = (f4){bv.x,bv.y,bv.z,bv.w};
            aB[i][t] = (f4){0.f,0.f,0.f,0.f};
        }
    }
    __builtin_amdgcn_s_setprio(1);
    #pragma unroll
    for (int ks=0; ks<2; ++ks){
        sh8 fA[NI], fB[NI];
        #pragma unroll
        for (int i=0;i<NI;++i){
            const int row = 48*w + nl + 16*i;
            fA[i] = *(const sh8*)&bufA[row*128 + ((64*ks + 16*hi) ^ rsw)];
            fB[i] = *(const sh8*)&bufB[row*128 + ((64*ks + 16*hi) ^ rsw)];
        }
        #pragma unroll
        for (int t=0;t<4;++t){
            sh8 af = *(const sh8*)&W1b[((16*t+nl)*64 + 32*ks + 8*hi)*2];
            #pragma unroll
            for (int i=0;i<NI;++i){
                aA[i][t] = __builtin_amdgcn_mfma_f32_16x16x32_bf16(af, fA[i], aA[i][t], 0,0,0);
                aB[i][t] = __builtin_amdgcn_mfma_f32_16x16x32_bf16(af, fB[i], aB[i][t], 0,0,0);
            }
        }
    }
    __builtin_amdgcn_s_setprio(0);
    // E2: h2 -> bufA, t2 -> bufB
    #pragma unroll
    for (int i=0;i<NI;++i){
        const int row = 48*w + nl + 16*i;
        #pragma unroll
        for (int t=0;t<4;++t){
            float v[4], tv[4];
            #pragma unroll
            for (int r=0;r<4;++r){
                float a = aA[i][t][r];
                v[r] = fmaxf(a, SLOPE*a);
                float q = aB[i][t][r];
                tv[r] = (a >= 0.f) ? q : SLOPE*q;
            }
            uint2 ph; ph.x = pk2(v[0],v[1]); ph.y = pk2(v[2],v[3]);
            *(uint2*)&bufA[row*128 + ((32*t + 8*hi) ^ rsw)] = ph;
            uint2 pt; pt.x = pk2(tv[0],tv[1]); pt.y = pk2(tv[2],tv[3]);
            *(uint2*)&bufB[row*128 + ((32*t + 8*hi) ^ rsw)] = pt;
        }
    }

    // ---------------- G3: L3 fwd + T3 tangent ----------------
    #pragma unroll
    for (int t=0;t<4;++t){
        float4 bv = *(const float4*)(bias2 + d*64 + 16*t + 4*hi);
        #pragma unroll
        for (int i=0;i<NI;++i){
            aA[i][t] = (f4){bv.x,bv.y,bv.z,bv.w};
            aB[i][t] = (f4){0.f,0.f,0.f,0.f};
        }
    }
    __builtin_amdgcn_s_setprio(1);
    #pragma unroll
    for (int ks=0; ks<2; ++ks){
        sh8 fA[NI], fB[NI];
        #pragma unroll
        for (int i=0;i<NI;++i){
            const int row = 48*w + nl + 16*i;
            fA[i] = *(const sh8*)&bufA[row*128 + ((64*ks + 16*hi) ^ rsw)];
            fB[i] = *(const sh8*)&bufB[row*128 + ((64*ks + 16*hi) ^ rsw)];
        }
        #pragma unroll
        for (int t=0;t<4;++t){
            sh8 af = *(const sh8*)&W2b[((16*t+nl)*64 + 32*ks + 8*hi)*2];
            #pragma unroll
            for (int i=0;i<NI;++i){
                aA[i][t] = __builtin_amdgcn_mfma_f32_16x16x32_bf16(af, fA[i], aA[i][t], 0,0,0);
                aB[i][t] = __builtin_amdgcn_mfma_f32_16x16x32_bf16(af, fB[i], aB[i][t], 0,0,0);
            }
        }
    }
    __builtin_amdgcn_s_setprio(0);

    // ---------------- head + logdet ----------------
    float res[NI], dres[NI];
    #pragma unroll
    for (int i=0;i<NI;++i){ res[i] = 0.f; dres[i] = 0.f; }
    #pragma unroll
    for (int t=0;t<4;++t){
        float4 ov = *(const float4*)(Wout + d*64 + 16*t + 4*hi);
        float wo[4] = {ov.x, ov.y, ov.z, ov.w};
        #pragma unroll
        for (int i=0;i<NI;++i){
            #pragma unroll
            for (int r=0;r<4;++r){
                float a  = aA[i][t][r];
                float h3 = fmaxf(a, SLOPE*a);
                res[i] = fmaf(wo[r], h3, res[i]);
                float q  = aB[i][t][r];
                float tv = (a >= 0.f) ? q : SLOPE*q;
                dres[i] = fmaf(wo[r], tv, dres[i]);
            }
        }
    }
    const float bo = boutp[d];
    float la[NI];
    #pragma unroll
    for (int i=0;i<NI;++i){
        res[i]  += __shfl_xor(res[i], 16);  res[i]  += __shfl_xor(res[i], 32);
        dres[i] += __shfl_xor(dres[i], 16); dres[i] += __shfl_xor(dres[i], 32);
        la[i] = __logf(fabsf(dres[i]));
    }
    if (hi == 0){
        #pragma unroll
        for (int i=0;i<NI;++i){
            int n = g*GW + 48*w + nl + 16*i;
            out[(size_t)n*DDIM + d] = res[i] + bo;
        }
    }

    // per-wave deterministic reduction (split by batch bucket)
    {
        int cb0 = (g*GW) / NWIN;
        float v0 = 0.f, v1 = 0.f;
        #pragma unroll
        for (int i=0;i<NI;++i){
            v0 += (bb[i] == cb0    ) ? la[i] : 0.f;
            v1 += (bb[i] == cb0 + 1) ? la[i] : 0.f;
        }
        #pragma unroll
        for (int s = 1; s < 16; s <<= 1){
            v0 += __shfl_xor(v0, s);
            v1 += __shfl_xor(v1, s);
        }
        if (lane == 0){
            red[((size_t)(g*4 + w)*16 + d)*2 + 0] = v0;
            red[((size_t)(g*4 + w)*16 + d)*2 + 1] = v1;
        }
    }

    // ---------------- fused final reduction: last finishing block ----------------
    __syncthreads();                       // all waves' red stores issued
    if (tid == 0){
        __threadfence();                   // publish red to device scope
        int old = atomicAdd((int*)(wsb + CNT_OFF), 1);
        lastflag = (old == NGR*DDIM - 1);  // 1360 participants (dummies returned)
        if (lastflag) *(int*)(wsb + CNT_OFF) = 0;
    }
    __syncthreads();
    if (lastflag){
        __threadfence();                   // acquire: other blocks' red visible
        float* sg = (float*)bufA;          // reuse LDS: sg0[340], sg1[340]
        // stage A: fold d for each (g,w); fixed order -> deterministic
        for (int gw = tid; gw < NGR*4; gw += 256){
            float s0 = 0.f, s1 = 0.f;
            #pragma unroll
            for (int dd=0; dd<DDIM; ++dd){
                s0 += red[((size_t)gw*16 + dd)*2 + 0];
                s1 += red[((size_t)gw*16 + dd)*2 + 1];
            }
            sg[gw] = s0; sg[512 + gw] = s1;
        }
        __syncthreads();
        // stage B: per-batch deterministic sum over groups
        if (tid < NB){
            const int b = tid;
            float s = 0.f;
            for (int gg=0; gg<NGR; ++gg){
                int cb0 = (gg*GW)/NWIN;
                if (cb0 == b){
                    #pragma unroll
                    for (int ww=0; ww<4; ++ww) s += sg[gg*4 + ww];
                }
                if (cb0 + 1 == b){
                    #pragma unroll
                    for (int ww=0; ww<4; ++ww) s += sg[512 + gg*4 + ww];
                }
            }
            out[(size_t)NTOT*DDIM + b] = s;
        }
    }
}

extern "C" void kernel_launch(void* const* d_in, const int* in_sizes, int n_in,
                              void* d_out, int out_size, void* d_ws, size_t ws_size,
                              hipStream_t stream) {
    const float* x    = (const float*)d_in[0];
    const float* W0   = (const float*)d_in[1];
    const float* b0   = (const float*)d_in[2];
    const float* W1   = (const float*)d_in[3];
    const float* b1   = (const float*)d_in[4];
    const float* W2   = (const float*)d_in[5];
    const float* b2   = (const float*)d_in[6];
    const float* Wout = (const float*)d_in[7];
    const float* bout = (const float*)d_in[8];
    float* out = (float*)d_out;
    unsigned char* wsb = (unsigned char*)d_ws;

    prep<<<(NPREP + 256)/256, 256, 0, stream>>>(W0, W1, W2, wsb);

    mlp<<<NGP*DDIM, 256, 0, stream>>>(x, b0, b1, b2, Wout, bout, wsb,
                                      (float*)(wsb + RED_OFF), out);
}

// Round 12
// 49.756 us; speedup vs baseline: 1.7890x; 1.7890x over previous
//
#include <hip/hip_runtime.h>
#include <hip/hip_bf16.h>
#include <math.h>

#define NB 32
#define SEQT 512
#define DDIM 16
#define NWIN 510
#define NTOT (NB*NWIN)      // 16320
#define SLOPE 0.2f
#define NI 3                // instances per wave (saturation point per r7-r10)
#define GW 192              // windows per block (4 waves * 3 inst * 16)
#define NGR 85              // real groups: 85*192 = 16320 exactly
#define NGP 88              // padded to multiple of 8 for XCD mapping

typedef __attribute__((ext_vector_type(8))) short sh8;   // 8 bf16
typedef __attribute__((ext_vector_type(4))) float f4;

static __device__ __forceinline__ unsigned short bfb(float f){
    union { __hip_bfloat16 h; unsigned short u; } cv;
    cv.h = __float2bfloat16(f);
    return cv.u;
}
static __device__ __forceinline__ unsigned pk2(float a, float b){
    return (unsigned)bfb(a) | ((unsigned)bfb(b) << 16);
}

__global__ __launch_bounds__(256, 3) void mlp(
    const float* __restrict__ x,
    const float* __restrict__ W0, const float* __restrict__ bias0,
    const float* __restrict__ W1, const float* __restrict__ bias1,
    const float* __restrict__ W2, const float* __restrict__ bias2,
    const float* __restrict__ Wout, const float* __restrict__ boutp,
    float* __restrict__ red, float* __restrict__ out)
{
    // barrier-free: wave w owns rows [48w, 48w+48). 3 instances per wave.
    __shared__ __align__(16) unsigned char bufA[GW*128];   // h1 -> h2 (in-place), 24 KB
    __shared__ __align__(16) unsigned char bufB[GW*128];   // t1 -> t2 (in-place), 24 KB

    const int tid  = threadIdx.x;
    const int lane = tid & 63;
    const int w    = tid >> 6;
    const int nl   = lane & 15;
    const int hi   = lane >> 4;
    const int rsw  = (nl & 7) << 4;

    // XCD-local decode: bid = (g&7) + 8*d + 128*(g>>3); all 16 d-blocks of a
    // group share bid%8 (same XCD under round-robin dispatch).
    const int bid = blockIdx.x;
    const int d   = (bid >> 3) & 15;
    const int g   = ((bid >> 7) << 3) | (bid & 7);
    if (g >= NGR) return;            // padded dummies

    const float* W0p = W0 + (size_t)d*64*33;    // rows 64 x 33
    const float* W1p = W1 + (size_t)d*4096;     // rows 64 x 64
    const float* W2p = W2 + (size_t)d*4096;

    int   bb[NI];
    float xxv[NI];
    union { uint4 u; sh8 s; } in[NI];
    #pragma unroll
    for (int i=0;i<NI;++i){
        int n = g*GW + 48*w + nl + 16*i;
        int b = n / NWIN, t = n - b*NWIN;
        bb[i] = b;
        const float* gp = x + (size_t)(b*SEQT + t)*DDIM + 8*hi;
        float4 p0 = ((const float4*)gp)[0];
        float4 p1 = ((const float4*)gp)[1];
        in[i].u.x = pk2(p0.x,p0.y); in[i].u.y = pk2(p0.z,p0.w);
        in[i].u.z = pk2(p1.x,p1.y); in[i].u.w = pk2(p1.z,p1.w);
        xxv[i] = x[(size_t)(b*SEQT + t + 2)*DDIM + d];
    }

    f4 aA[NI][4], aB[NI][4];

    // ---------------- L1 (K=32 MFMA + fp32 rank-1 for col 32) ----------------
    #pragma unroll
    for (int t=0;t<4;++t){
        float4 bv = *(const float4*)(bias0 + d*64 + 16*t + 4*hi);
        #pragma unroll
        for (int i=0;i<NI;++i) aA[i][t] = (f4){bv.x,bv.y,bv.z,bv.w};
    }
    __builtin_amdgcn_s_setprio(1);
    #pragma unroll
    for (int t=0;t<4;++t){
        // W0 row is 33-stride (4B-aligned only) -> scalar loads + fused cvt
        const float* wr = W0p + (16*t+nl)*33 + 8*hi;
        union { uint4 u; sh8 s; } af;
        af.u.x = pk2(wr[0], wr[1]); af.u.y = pk2(wr[2], wr[3]);
        af.u.z = pk2(wr[4], wr[5]); af.u.w = pk2(wr[6], wr[7]);
        #pragma unroll
        for (int i=0;i<NI;++i)
            aA[i][t] = __builtin_amdgcn_mfma_f32_16x16x32_bf16(af.s, in[i].s, aA[i][t], 0,0,0);
    }
    __builtin_amdgcn_s_setprio(0);

    // ---- E1: rank-1 + act -> bufA ; t1 = deriv1.*wcol -> bufB ----
    {
        #pragma unroll
        for (int t=0;t<4;++t){
            float wc[4];
            #pragma unroll
            for (int r=0;r<4;++r)
                wc[r] = W0p[(16*t + 4*hi + r)*33 + 32];   // col 32 (rank-1 column)
            #pragma unroll
            for (int i=0;i<NI;++i){
                const int row = 48*w + nl + 16*i;
                float v[4], tv[4];
                #pragma unroll
                for (int r=0;r<4;++r){
                    float a = fmaf(wc[r], xxv[i], aA[i][t][r]);
                    v[r]  = fmaxf(a, SLOPE*a);
                    tv[r] = (a >= 0.f) ? wc[r] : SLOPE*wc[r];
                }
                uint2 ph; ph.x = pk2(v[0],v[1]);  ph.y = pk2(v[2],v[3]);
                *(uint2*)&bufA[row*128 + ((32*t + 8*hi) ^ rsw)] = ph;
                uint2 pt; pt.x = pk2(tv[0],tv[1]); pt.y = pk2(tv[2],tv[3]);
                *(uint2*)&bufB[row*128 + ((32*t + 8*hi) ^ rsw)] = pt;
            }
        }
    }

    // ---------------- G2: L2 fwd + T2 tangent, shared A-frags ----------------
    #pragma unroll
    for (int t=0;t<4;++t){
        float4 bv = *(const float4*)(bias1 + d*64 + 16*t + 4*hi);
        #pragma unroll
        for (int i=0;i<NI;++i){
            aA[i][t] = (f4){bv.x,bv.y,bv.z,bv.w};
            aB[i][t] = (f4){0.f,0.f,0.f,0.f};
        }
    }
    __builtin_amdgcn_s_setprio(1);
    #pragma unroll
    for (int ks=0; ks<2; ++ks){
        sh8 fA[NI], fB[NI];
        #pragma unroll
        for (int i=0;i<NI;++i){
            const int row = 48*w + nl + 16*i;
            fA[i] = *(const sh8*)&bufA[row*128 + ((64*ks + 16*hi) ^ rsw)];
            fB[i] = *(const sh8*)&bufB[row*128 + ((64*ks + 16*hi) ^ rsw)];
        }
        #pragma unroll
        for (int t=0;t<4;++t){
            const float* wr = W1p + (16*t+nl)*64 + 32*ks + 8*hi;   // 16B-aligned
            float4 q0 = ((const float4*)wr)[0];
            float4 q1 = ((const float4*)wr)[1];
            union { uint4 u; sh8 s; } af;
            af.u.x = pk2(q0.x,q0.y); af.u.y = pk2(q0.z,q0.w);
            af.u.z = pk2(q1.x,q1.y); af.u.w = pk2(q1.z,q1.w);
            #pragma unroll
            for (int i=0;i<NI;++i){
                aA[i][t] = __builtin_amdgcn_mfma_f32_16x16x32_bf16(af.s, fA[i], aA[i][t], 0,0,0);
                aB[i][t] = __builtin_amdgcn_mfma_f32_16x16x32_bf16(af.s, fB[i], aB[i][t], 0,0,0);
            }
        }
    }
    __builtin_amdgcn_s_setprio(0);
    // E2: h2 -> bufA, t2 -> bufB
    #pragma unroll
    for (int i=0;i<NI;++i){
        const int row = 48*w + nl + 16*i;
        #pragma unroll
        for (int t=0;t<4;++t){
            float v[4], tv[4];
            #pragma unroll
            for (int r=0;r<4;++r){
                float a = aA[i][t][r];
                v[r] = fmaxf(a, SLOPE*a);
                float q = aB[i][t][r];
                tv[r] = (a >= 0.f) ? q : SLOPE*q;
            }
            uint2 ph; ph.x = pk2(v[0],v[1]); ph.y = pk2(v[2],v[3]);
            *(uint2*)&bufA[row*128 + ((32*t + 8*hi) ^ rsw)] = ph;
            uint2 pt; pt.x = pk2(tv[0],tv[1]); pt.y = pk2(tv[2],tv[3]);
            *(uint2*)&bufB[row*128 + ((32*t + 8*hi) ^ rsw)] = pt;
        }
    }

    // ---------------- G3: L3 fwd + T3 tangent ----------------
    #pragma unroll
    for (int t=0;t<4;++t){
        float4 bv = *(const float4*)(bias2 + d*64 + 16*t + 4*hi);
        #pragma unroll
        for (int i=0;i<NI;++i){
            aA[i][t] = (f4){bv.x,bv.y,bv.z,bv.w};
            aB[i][t] = (f4){0.f,0.f,0.f,0.f};
        }
    }
    __builtin_amdgcn_s_setprio(1);
    #pragma unroll
    for (int ks=0; ks<2; ++ks){
        sh8 fA[NI], fB[NI];
        #pragma unroll
        for (int i=0;i<NI;++i){
            const int row = 48*w + nl + 16*i;
            fA[i] = *(const sh8*)&bufA[row*128 + ((64*ks + 16*hi) ^ rsw)];
            fB[i] = *(const sh8*)&bufB[row*128 + ((64*ks + 16*hi) ^ rsw)];
        }
        #pragma unroll
        for (int t=0;t<4;++t){
            const float* wr = W2p + (16*t+nl)*64 + 32*ks + 8*hi;
            float4 q0 = ((const float4*)wr)[0];
            float4 q1 = ((const float4*)wr)[1];
            union { uint4 u; sh8 s; } af;
            af.u.x = pk2(q0.x,q0.y); af.u.y = pk2(q0.z,q0.w);
            af.u.z = pk2(q1.x,q1.y); af.u.w = pk2(q1.z,q1.w);
            #pragma unroll
            for (int i=0;i<NI;++i){
                aA[i][t] = __builtin_amdgcn_mfma_f32_16x16x32_bf16(af.s, fA[i], aA[i][t], 0,0,0);
                aB[i][t] = __builtin_amdgcn_mfma_f32_16x16x32_bf16(af.s, fB[i], aB[i][t], 0,0,0);
            }
        }
    }
    __builtin_amdgcn_s_setprio(0);

    // ---------------- head + logdet ----------------
    float res[NI], dres[NI];
    #pragma unroll
    for (int i=0;i<NI;++i){ res[i] = 0.f; dres[i] = 0.f; }
    #pragma unroll
    for (int t=0;t<4;++t){
        float4 ov = *(const float4*)(Wout + d*64 + 16*t + 4*hi);
        float wo[4] = {ov.x, ov.y, ov.z, ov.w};
        #pragma unroll
        for (int i=0;i<NI;++i){
            #pragma unroll
            for (int r=0;r<4;++r){
                float a  = aA[i][t][r];
                float h3 = fmaxf(a, SLOPE*a);
                res[i] = fmaf(wo[r], h3, res[i]);
                float q  = aB[i][t][r];
                float tv = (a >= 0.f) ? q : SLOPE*q;
                dres[i] = fmaf(wo[r], tv, dres[i]);
            }
        }
    }
    const float bo = boutp[d];
    float la[NI];
    #pragma unroll
    for (int i=0;i<NI;++i){
        res[i]  += __shfl_xor(res[i], 16);  res[i]  += __shfl_xor(res[i], 32);
        dres[i] += __shfl_xor(dres[i], 16); dres[i] += __shfl_xor(dres[i], 32);
        la[i] = __logf(fabsf(dres[i]));
    }
    if (hi == 0){
        #pragma unroll
        for (int i=0;i<NI;++i){
            int n = g*GW + 48*w + nl + 16*i;
            out[(size_t)n*DDIM + d] = res[i] + bo;
        }
    }

    // per-wave deterministic reduction (split by batch bucket)
    {
        int cb0 = (g*GW) / NWIN;
        float v0 = 0.f, v1 = 0.f;
        #pragma unroll
        for (int i=0;i<NI;++i){
            v0 += (bb[i] == cb0    ) ? la[i] : 0.f;
            v1 += (bb[i] == cb0 + 1) ? la[i] : 0.f;
        }
        #pragma unroll
        for (int s = 1; s < 16; s <<= 1){
            v0 += __shfl_xor(v0, s);
            v1 += __shfl_xor(v1, s);
        }
        if (lane == 0){
            red[((size_t)(g*4 + w)*16 + d)*2 + 0] = v0;
            red[((size_t)(g*4 + w)*16 + d)*2 + 1] = v1;
        }
    }
}

__global__ void final_red(const float* __restrict__ red, float* __restrict__ sld){
    __shared__ float pp[DDIM][16];
    const int b = blockIdx.x;
    const int tid = threadIdx.x;
    const int d = tid & 15, j = tid >> 4;
    float s = 0.f;
    for (int gw = j; gw < NGR*4; gw += 16){
        int g = gw >> 2;
        int cb0 = (g*GW)/NWIN;
        const float* r = red + ((size_t)gw*16 + d)*2;
        if (cb0     == b) s += r[0];
        if (cb0 + 1 == b) s += r[1];
    }
    pp[d][j] = s;
    __syncthreads();
    if (tid < DDIM){
        float a = 0.f;
        #pragma unroll
        for (int k=0;k<16;++k) a += pp[tid][k];
        pp[tid][0] = a;
    }
    __syncthreads();
    if (tid == 0){
        float a = 0.f;
        #pragma unroll
        for (int dd=0; dd<DDIM; ++dd) a += pp[dd][0];
        sld[b] = a;
    }
}

extern "C" void kernel_launch(void* const* d_in, const int* in_sizes, int n_in,
                              void* d_out, int out_size, void* d_ws, size_t ws_size,
                              hipStream_t stream) {
    const float* x    = (const float*)d_in[0];
    const float* W0   = (const float*)d_in[1];
    const float* b0   = (const float*)d_in[2];
    const float* W1   = (const float*)d_in[3];
    const float* b1   = (const float*)d_in[4];
    const float* W2   = (const float*)d_in[5];
    const float* b2   = (const float*)d_in[6];
    const float* Wout = (const float*)d_in[7];
    const float* bout = (const float*)d_in[8];
    float* out = (float*)d_out;
    float* red = (float*)d_ws;

    mlp<<<NGP*DDIM, 256, 0, stream>>>(x, W0, b0, W1, b1, W2, b2, Wout, bout,
                                      red, out);

    final_red<<<NB, 256, 0, stream>>>(red, out + (size_t)NTOT*DDIM);
}

// Round 13
// 42.805 us; speedup vs baseline: 2.0795x; 1.1624x over previous
//
#include <hip/hip_runtime.h>
#include <hip/hip_bf16.h>
#include <math.h>

#define NB 32
#define SEQT 512
#define DDIM 16
#define NWIN 510
#define NTOT (NB*NWIN)      // 16320
#define SLOPE 0.2f
#define NI 3                // instances per wave
#define GW 192              // windows per block (4 waves * 3 inst * 16)
#define NGR 85              // real groups: 85*192 = 16320 exactly
#define NGP 88              // padded to multiple of 8 for XCD mapping

typedef __attribute__((ext_vector_type(8))) short sh8;   // 8 bf16
typedef __attribute__((ext_vector_type(4))) float f4;

// ws byte offsets
#define W0B_OFF 0            // bf16 [16][64][32]   (k = 0..31 only)
#define W1B_OFF 65536        // bf16 [16][64][64]
#define W2B_OFF 196608       // bf16 [16][64][64]
#define WCOL_OFF 327680      // f32  [16][64]  = W0[d][h][32]
#define RED_OFF 331776       // f32  [340][16][2]
#define NPREP 164864

static __device__ __forceinline__ unsigned short bfb(float f){
    union { __hip_bfloat16 h; unsigned short u; } cv;
    cv.h = __float2bfloat16(f);
    return cv.u;
}
static __device__ __forceinline__ unsigned pk2(float a, float b){
    return (unsigned)bfb(a) | ((unsigned)bfb(b) << 16);
}

__global__ void prep(const float* __restrict__ W0, const float* __restrict__ W1,
                     const float* __restrict__ W2, unsigned char* __restrict__ wsb){
    int e = blockIdx.x*256 + threadIdx.x;
    if (e < 32768){
        unsigned short* W0b = (unsigned short*)(wsb + W0B_OFF);
        int d = e >> 11, r = e & 2047, h = r >> 5, k = r & 31;
        W0b[e] = bfb(W0[(d*64 + h)*33 + k]);
    } else if (e < 98304){
        ((unsigned short*)(wsb + W1B_OFF))[e - 32768] = bfb(W1[e - 32768]);
    } else if (e < 163840){
        ((unsigned short*)(wsb + W2B_OFF))[e - 98304] = bfb(W2[e - 98304]);
    } else if (e < NPREP){
        int i = e - 163840;
        int d = i >> 6, h = i & 63;
        ((float*)(wsb + WCOL_OFF))[i] = W0[(d*64 + h)*33 + 32];
    }
}

__global__ __launch_bounds__(256, 3) void mlp(
    const float* __restrict__ x,
    const float* __restrict__ bias0, const float* __restrict__ bias1,
    const float* __restrict__ bias2,
    const float* __restrict__ Wout, const float* __restrict__ boutp,
    const unsigned char* __restrict__ wsb,
    float* __restrict__ red, float* __restrict__ out)
{
    // barrier-free: wave w owns rows [48w, 48w+48). 3 instances per wave.
    __shared__ __align__(16) unsigned char bufA[GW*128];   // h1 -> h2 (in-place), 24 KB
    __shared__ __align__(16) unsigned char bufB[GW*128];   // t1 -> t2 (in-place), 24 KB

    const int tid  = threadIdx.x;
    const int lane = tid & 63;
    const int w    = tid >> 6;
    const int nl   = lane & 15;
    const int hi   = lane >> 4;
    const int rsw  = (nl & 7) << 4;

    // XCD-local decode: bid = (g&7) + 8*d + 128*(g>>3); all 16 d-blocks of a
    // group share bid%8 (same XCD under round-robin dispatch).
    const int bid = blockIdx.x;
    const int d   = (bid >> 3) & 15;
    const int g   = ((bid >> 7) << 3) | (bid & 7);
    if (g >= NGR) return;            // padded dummies

    const unsigned char* W0b = wsb + W0B_OFF + d*4096;
    const unsigned char* W1b = wsb + W1B_OFF + d*8192;
    const unsigned char* W2b = wsb + W2B_OFF + d*8192;

    int   bb[NI];
    float xxv[NI];
    union { uint4 u; sh8 s; } in[NI];
    #pragma unroll
    for (int i=0;i<NI;++i){
        int n = g*GW + 48*w + nl + 16*i;
        int b = n / NWIN, t = n - b*NWIN;
        bb[i] = b;
        const float* gp = x + (size_t)(b*SEQT + t)*DDIM + 8*hi;
        float4 p0 = ((const float4*)gp)[0];
        float4 p1 = ((const float4*)gp)[1];
        in[i].u.x = pk2(p0.x,p0.y); in[i].u.y = pk2(p0.z,p0.w);
        in[i].u.z = pk2(p1.x,p1.y); in[i].u.w = pk2(p1.z,p1.w);
        xxv[i] = x[(size_t)(b*SEQT + t + 2)*DDIM + d];
    }

    f4 aA[NI][4], aB[NI][4];

    // ---------------- L1 (K=32 MFMA + fp32 rank-1 for col 32) ----------------
    #pragma unroll
    for (int t=0;t<4;++t){
        float4 bv = *(const float4*)(bias0 + d*64 + 16*t + 4*hi);
        #pragma unroll
        for (int i=0;i<NI;++i) aA[i][t] = (f4){bv.x,bv.y,bv.z,bv.w};
    }
    __builtin_amdgcn_s_setprio(1);
    #pragma unroll
    for (int t=0;t<4;++t){
        sh8 af = *(const sh8*)&W0b[((16*t+nl)*32 + 8*hi)*2];
        #pragma unroll
        for (int i=0;i<NI;++i)
            aA[i][t] = __builtin_amdgcn_mfma_f32_16x16x32_bf16(af, in[i].s, aA[i][t], 0,0,0);
    }
    __builtin_amdgcn_s_setprio(0);

    // ---- E1: rank-1 + act -> bufA ; t1 = deriv1.*wcol -> bufB ----
    {
        const float* wcolp = (const float*)(wsb + WCOL_OFF) + d*64;
        #pragma unroll
        for (int t=0;t<4;++t){
            float4 wv = *(const float4*)(wcolp + 16*t + 4*hi);
            float wc[4] = {wv.x, wv.y, wv.z, wv.w};
            #pragma unroll
            for (int i=0;i<NI;++i){
                const int row = 48*w + nl + 16*i;
                float v[4], tv[4];
                #pragma unroll
                for (int r=0;r<4;++r){
                    float a = fmaf(wc[r], xxv[i], aA[i][t][r]);
                    v[r]  = fmaxf(a, SLOPE*a);
                    tv[r] = (a >= 0.f) ? wc[r] : SLOPE*wc[r];
                }
                uint2 ph; ph.x = pk2(v[0],v[1]);  ph.y = pk2(v[2],v[3]);
                *(uint2*)&bufA[row*128 + ((32*t + 8*hi) ^ rsw)] = ph;
                uint2 pt; pt.x = pk2(tv[0],tv[1]); pt.y = pk2(tv[2],tv[3]);
                *(uint2*)&bufB[row*128 + ((32*t + 8*hi) ^ rsw)] = pt;
            }
        }
    }

    // ---------------- G2: L2 fwd + T2 tangent, shared A-frags ----------------
    #pragma unroll
    for (int t=0;t<4;++t){
        float4 bv = *(const float4*)(bias1 + d*64 + 16*t + 4*hi);
        #pragma unroll
        for (int i=0;i<NI;++i){
            aA[i][t] = (f4){bv.x,bv.y,bv.z,bv.w};
            aB[i][t] = (f4){0.f,0.f,0.f,0.f};
        }
    }
    __builtin_amdgcn_s_setprio(1);
    #pragma unroll
    for (int ks=0; ks<2; ++ks){
        sh8 fA[NI], fB[NI];
        #pragma unroll
        for (int i=0;i<NI;++i){
            const int row = 48*w + nl + 16*i;
            fA[i] = *(const sh8*)&bufA[row*128 + ((64*ks + 16*hi) ^ rsw)];
            fB[i] = *(const sh8*)&bufB[row*128 + ((64*ks + 16*hi) ^ rsw)];
        }
        #pragma unroll
        for (int t=0;t<4;++t){
            sh8 af = *(const sh8*)&W1b[((16*t+nl)*64 + 32*ks + 8*hi)*2];
            #pragma unroll
            for (int i=0;i<NI;++i){
                aA[i][t] = __builtin_amdgcn_mfma_f32_16x16x32_bf16(af, fA[i], aA[i][t], 0,0,0);
                aB[i][t] = __builtin_amdgcn_mfma_f32_16x16x32_bf16(af, fB[i], aB[i][t], 0,0,0);
            }
        }
    }
    __builtin_amdgcn_s_setprio(0);
    // E2: h2 -> bufA, t2 -> bufB
    #pragma unroll
    for (int i=0;i<NI;++i){
        const int row = 48*w + nl + 16*i;
        #pragma unroll
        for (int t=0;t<4;++t){
            float v[4], tv[4];
            #pragma unroll
            for (int r=0;r<4;++r){
                float a = aA[i][t][r];
                v[r] = fmaxf(a, SLOPE*a);
                float q = aB[i][t][r];
                tv[r] = (a >= 0.f) ? q : SLOPE*q;
            }
            uint2 ph; ph.x = pk2(v[0],v[1]); ph.y = pk2(v[2],v[3]);
            *(uint2*)&bufA[row*128 + ((32*t + 8*hi) ^ rsw)] = ph;
            uint2 pt; pt.x = pk2(tv[0],tv[1]); pt.y = pk2(tv[2],tv[3]);
            *(uint2*)&bufB[row*128 + ((32*t + 8*hi) ^ rsw)] = pt;
        }
    }

    // ---------------- G3: L3 fwd + T3 tangent ----------------
    #pragma unroll
    for (int t=0;t<4;++t){
        float4 bv = *(const float4*)(bias2 + d*64 + 16*t + 4*hi);
        #pragma unroll
        for (int i=0;i<NI;++i){
            aA[i][t] = (f4){bv.x,bv.y,bv.z,bv.w};
            aB[i][t] = (f4){0.f,0.f,0.f,0.f};
        }
    }
    __builtin_amdgcn_s_setprio(1);
    #pragma unroll
    for (int ks=0; ks<2; ++ks){
        sh8 fA[NI], fB[NI];
        #pragma unroll
        for (int i=0;i<NI;++i){
            const int row = 48*w + nl + 16*i;
            fA[i] = *(const sh8*)&bufA[row*128 + ((64*ks + 16*hi) ^ rsw)];
            fB[i] = *(const sh8*)&bufB[row*128 + ((64*ks + 16*hi) ^ rsw)];
        }
        #pragma unroll
        for (int t=0;t<4;++t){
            sh8 af = *(const sh8*)&W2b[((16*t+nl)*64 + 32*ks + 8*hi)*2];
            #pragma unroll
            for (int i=0;i<NI;++i){
                aA[i][t] = __builtin_amdgcn_mfma_f32_16x16x32_bf16(af, fA[i], aA[i][t], 0,0,0);
                aB[i][t] = __builtin_amdgcn_mfma_f32_16x16x32_bf16(af, fB[i], aB[i][t], 0,0,0);
            }
        }
    }
    __builtin_amdgcn_s_setprio(0);

    // ---------------- head + logdet ----------------
    float res[NI], dres[NI];
    #pragma unroll
    for (int i=0;i<NI;++i){ res[i] = 0.f; dres[i] = 0.f; }
    #pragma unroll
    for (int t=0;t<4;++t){
        float4 ov = *(const float4*)(Wout + d*64 + 16*t + 4*hi);
        float wo[4] = {ov.x, ov.y, ov.z, ov.w};
        #pragma unroll
        for (int i=0;i<NI;++i){
            #pragma unroll
            for (int r=0;r<4;++r){
                float a  = aA[i][t][r];
                float h3 = fmaxf(a, SLOPE*a);
                res[i] = fmaf(wo[r], h3, res[i]);
                float q  = aB[i][t][r];
                float tv = (a >= 0.f) ? q : SLOPE*q;
                dres[i] = fmaf(wo[r], tv, dres[i]);
            }
        }
    }
    const float bo = boutp[d];
    float la[NI];
    #pragma unroll
    for (int i=0;i<NI;++i){
        res[i]  += __shfl_xor(res[i], 16);  res[i]  += __shfl_xor(res[i], 32);
        dres[i] += __shfl_xor(dres[i], 16); dres[i] += __shfl_xor(dres[i], 32);
        la[i] = __logf(fabsf(dres[i]));
    }
    if (hi == 0){
        #pragma unroll
        for (int i=0;i<NI;++i){
            int n = g*GW + 48*w + nl + 16*i;
            out[(size_t)n*DDIM + d] = res[i] + bo;
        }
    }

    // per-wave deterministic reduction (split by batch bucket)
    {
        int cb0 = (g*GW) / NWIN;
        float v0 = 0.f, v1 = 0.f;
        #pragma unroll
        for (int i=0;i<NI;++i){
            v0 += (bb[i] == cb0    ) ? la[i] : 0.f;
            v1 += (bb[i] == cb0 + 1) ? la[i] : 0.f;
        }
        #pragma unroll
        for (int s = 1; s < 16; s <<= 1){
            v0 += __shfl_xor(v0, s);
            v1 += __shfl_xor(v1, s);
        }
        if (lane == 0){
            red[((size_t)(g*4 + w)*16 + d)*2 + 0] = v0;
            red[((size_t)(g*4 + w)*16 + d)*2 + 1] = v1;
        }
    }
}

__global__ void final_red(const float* __restrict__ red, float* __restrict__ sld){
    __shared__ float pp[DDIM][16];
    const int b = blockIdx.x;
    const int tid = threadIdx.x;
    const int d = tid & 15, j = tid >> 4;
    float s = 0.f;
    for (int gw = j; gw < NGR*4; gw += 16){
        int g = gw >> 2;
        int cb0 = (g*GW)/NWIN;
        const float* r = red + ((size_t)gw*16 + d)*2;
        if (cb0     == b) s += r[0];
        if (cb0 + 1 == b) s += r[1];
    }
    pp[d][j] = s;
    __syncthreads();
    if (tid < DDIM){
        float a = 0.f;
        #pragma unroll
        for (int k=0;k<16;++k) a += pp[tid][k];
        pp[tid][0] = a;
    }
    __syncthreads();
    if (tid == 0){
        float a = 0.f;
        #pragma unroll
        for (int dd=0; dd<DDIM; ++dd) a += pp[dd][0];
        sld[b] = a;
    }
}

extern "C" void kernel_launch(void* const* d_in, const int* in_sizes, int n_in,
                              void* d_out, int out_size, void* d_ws, size_t ws_size,
                              hipStream_t stream) {
    const float* x    = (const float*)d_in[0];
    const float* W0   = (const float*)d_in[1];
    const float* b0   = (const float*)d_in[2];
    const float* W1   = (const float*)d_in[3];
    const float* b1   = (const float*)d_in[4];
    const float* W2   = (const float*)d_in[5];
    const float* b2   = (const float*)d_in[6];
    const float* Wout = (const float*)d_in[7];
    const float* bout = (const float*)d_in[8];
    float* out = (float*)d_out;
    unsigned char* wsb = (unsigned char*)d_ws;

    prep<<<(NPREP + 255)/256, 256, 0, stream>>>(W0, W1, W2, wsb);

    mlp<<<NGP*DDIM, 256, 0, stream>>>(x, b0, b1, b2, Wout, bout, wsb,
                                      (float*)(wsb + RED_OFF), out);

    final_red<<<NB, 256, 0, stream>>>((const float*)(wsb + RED_OFF),
                                      out + (size_t)NTOT*DDIM);
}